// Round 1
// baseline (520.005 us; speedup 1.0000x reference)
//
#include <hip/hip_runtime.h>

// CRF-RNN forward, MI355X. Internal layout is channel-last (H,W,D) so every
// per-pixel op reads/writes 16 contiguous floats (float4-vectorized), and the
// final iteration writes d_out (which is (H,W,D)) directly.

constexpr int H = 512, W = 512, D = 16;
constexpr int HW = H * W;
constexpr int NUM_ITERS = 5;
constexpr float INV2A = 1.0f / (2.0f * 160.0f * 160.0f);
constexpr float INV2B = 1.0f / (2.0f * 3.0f * 3.0f);

// workspace layout (float offsets)
constexpr size_t OFF_U  = 0;                         // unaries, (H,W,D)
constexpr size_t OFF_Q  = OFF_U + (size_t)HW * D;    // q,       (H,W,D)
constexpr size_t OFF_P  = OFF_Q + (size_t)HW * D;    // softmax, (H,W,D)
constexpr size_t OFF_T  = OFF_P + (size_t)HW * D;    // vconv,   (H,W,D)
constexpr size_t OFF_BN = OFF_T + (size_t)HW * D;    // bilateral norm (H,W)
constexpr size_t OFF_SV = OFF_BN + HW;               // 1D spatial norm factor [512]
constexpr size_t OFF_KG = OFF_SV + 512;              // gauss taps [19] (pad 32)
constexpr size_t OFF_M1 = OFF_KG + 32;               // C@Sw, 16x16 row-major
constexpr size_t OFF_M2 = OFF_M1 + 256;              // C@Bw, 16x16 row-major
// total = 17,040,416 floats = ~68.2 MB

// ---------------------------------------------------------------- init tables
__global__ void k_init(const float* __restrict__ Sw, const float* __restrict__ Bw,
                       const float* __restrict__ Cm, float* __restrict__ ws) {
    __shared__ float kg[19];
    int tid = threadIdx.x;
    if (tid < 19) { int t = tid - 9; kg[tid] = expf(-(float)(t * t) / 18.0f); }
    __syncthreads();
    if (tid < 19) ws[OFF_KG + tid] = kg[tid];
    if (tid < 512) {
        float s = 0.0f;
        for (int t = -9; t <= 9; ++t) {
            int yy = tid + t;
            if (yy >= 0 && yy < 512) s += kg[t + 9];
        }
        ws[OFF_SV + tid] = s;
    }
    if (tid < 256) {
        int r = tid >> 4, c = tid & 15;
        float a = 0.0f, b = 0.0f;
        for (int k = 0; k < 16; ++k) {
            float cv = Cm[r * 16 + k];
            a += cv * Sw[k * 16 + c];
            b += cv * Bw[k * 16 + c];
        }
        ws[OFF_M1 + tid] = a;
        ws[OFF_M2 + tid] = b;
    }
}

// ----------------------------------- unaries (transpose to HWD) + bilateral norm
__global__ __launch_bounds__(256) void k_prep(const float* __restrict__ img,
                                              const float* __restrict__ ub,
                                              const float* __restrict__ ug,
                                              const float* __restrict__ pbw,
                                              const float* __restrict__ pgw,
                                              float* __restrict__ ws) {
    int pix = blockIdx.x * 256 + threadIdx.x;
    float bw = pbw[0], gw = pgw[0];
    int y = pix >> 9, x = pix & 511;

    float u[16];
#pragma unroll
    for (int i = 0; i < 16; ++i)
        u[i] = ub[(size_t)i * HW + pix] * bw + ug[(size_t)i * HW + pix] * gw;
    float4* U4 = (float4*)(ws + OFF_U);
#pragma unroll
    for (int j = 0; j < 4; ++j)
        U4[(size_t)pix * 4 + j] = make_float4(u[4 * j], u[4 * j + 1], u[4 * j + 2], u[4 * j + 3]);

    float r0 = img[pix * 3 + 0], g0 = img[pix * 3 + 1], b0 = img[pix * 3 + 2];
    float s = 0.0f;
#pragma unroll
    for (int dy = -2; dy <= 2; ++dy) {
        int yy = y + dy;
        if (yy < 0 || yy >= H) continue;
#pragma unroll
        for (int dx = -2; dx <= 2; ++dx) {
            int xx = x + dx;
            if (xx < 0 || xx >= W) continue;
            int np = yy * W + xx;
            float dr = r0 - img[np * 3 + 0];
            float dg = g0 - img[np * 3 + 1];
            float db = b0 - img[np * 3 + 2];
            s += __expf(-(float)(dy * dy + dx * dx) * INV2A
                        - (dr * dr + dg * dg + db * db) * INV2B);
        }
    }
    ws[OFF_BN + pix] = s;
}

// ---------------------------------------------------------------- softmax over D
__global__ __launch_bounds__(256) void k_softmax(const float* __restrict__ src,
                                                 float* __restrict__ dst) {
    int pix = blockIdx.x * 256 + threadIdx.x;
    const float4* s4 = (const float4*)src;
    float v[16];
#pragma unroll
    for (int j = 0; j < 4; ++j) {
        float4 t = s4[(size_t)pix * 4 + j];
        v[4 * j + 0] = t.x; v[4 * j + 1] = t.y; v[4 * j + 2] = t.z; v[4 * j + 3] = t.w;
    }
    float m = v[0];
#pragma unroll
    for (int i = 1; i < 16; ++i) m = fmaxf(m, v[i]);
    float sum = 0.0f;
#pragma unroll
    for (int i = 0; i < 16; ++i) { v[i] = __expf(v[i] - m); sum += v[i]; }
    float inv = 1.0f / sum;
    float4* d4 = (float4*)dst;
#pragma unroll
    for (int j = 0; j < 4; ++j)
        d4[(size_t)pix * 4 + j] = make_float4(v[4 * j] * inv, v[4 * j + 1] * inv,
                                              v[4 * j + 2] * inv, v[4 * j + 3] * inv);
}

// ------------------------------------------------- vertical 19-tap gaussian conv
// one thread per (pixel, channel-quad): perfectly coalesced float4 streams
__global__ __launch_bounds__(256) void k_convv(const float* __restrict__ ws,
                                               const float4* __restrict__ P4,
                                               float4* __restrict__ T4) {
    int idx = blockIdx.x * 256 + threadIdx.x;  // 0 .. HW*4
    int c4 = idx & 3;
    int pix = idx >> 2;
    int y = pix >> 9, x = pix & 511;
    float kg[19];
#pragma unroll
    for (int t = 0; t < 19; ++t) kg[t] = ws[OFF_KG + t];
    float4 acc = make_float4(0.f, 0.f, 0.f, 0.f);
#pragma unroll
    for (int t = 0; t < 19; ++t) {
        int yy = y + t - 9;
        if (yy >= 0 && yy < H) {
            float4 p = P4[(size_t)(yy * W + x) * 4 + c4];
            float k = kg[t];
            acc.x += k * p.x; acc.y += k * p.y; acc.z += k * p.z; acc.w += k * p.w;
        }
    }
    T4[(size_t)pix * 4 + c4] = acc;
}

// ------------- fused: horizontal conv + /snorm + bilateral + /bnorm + matmuls + q
__global__ __launch_bounds__(256) void k_combine(const float* __restrict__ ws,
                                                 const float* __restrict__ img,
                                                 float* __restrict__ dst) {
    __shared__ float4 sM1[64], sM2[64];
    int tid = threadIdx.x;
    if (tid < 64) {
        sM1[tid] = ((const float4*)(ws + OFF_M1))[tid];
        sM2[tid] = ((const float4*)(ws + OFF_M2))[tid];
    }
    __syncthreads();

    int pix = blockIdx.x * 256 + tid;
    int y = pix >> 9, x = pix & 511;

    float kg[19];
#pragma unroll
    for (int t = 0; t < 19; ++t) kg[t] = ws[OFF_KG + t];

    // horizontal 19-tap conv over T
    const float4* T4 = (const float4*)(ws + OFF_T);
    float sp[16];
#pragma unroll
    for (int i = 0; i < 16; ++i) sp[i] = 0.0f;
#pragma unroll
    for (int t = 0; t < 19; ++t) {
        int xx = x + t - 9;
        if (xx >= 0 && xx < W) {
            const float4* Tp = T4 + (size_t)(y * W + xx) * 4;
            float k = kg[t];
#pragma unroll
            for (int j = 0; j < 4; ++j) {
                float4 v = Tp[j];
                sp[4 * j + 0] += k * v.x; sp[4 * j + 1] += k * v.y;
                sp[4 * j + 2] += k * v.z; sp[4 * j + 3] += k * v.w;
            }
        }
    }
    float inv_sn = 1.0f / (ws[OFF_SV + y] * ws[OFF_SV + x]);
#pragma unroll
    for (int i = 0; i < 16; ++i) sp[i] *= inv_sn;

    // bilateral 5x5 over P
    const float4* P4 = (const float4*)(ws + OFF_P);
    float bl[16];
#pragma unroll
    for (int i = 0; i < 16; ++i) bl[i] = 0.0f;
    float r0 = img[pix * 3 + 0], g0 = img[pix * 3 + 1], b0 = img[pix * 3 + 2];
#pragma unroll
    for (int dy = -2; dy <= 2; ++dy) {
        int yy = y + dy;
        if (yy < 0 || yy >= H) continue;
#pragma unroll
        for (int dx = -2; dx <= 2; ++dx) {
            int xx = x + dx;
            if (xx < 0 || xx >= W) continue;
            int np = yy * W + xx;
            float dr = r0 - img[np * 3 + 0];
            float dg = g0 - img[np * 3 + 1];
            float db = b0 - img[np * 3 + 2];
            float wgt = __expf(-(float)(dy * dy + dx * dx) * INV2A
                               - (dr * dr + dg * dg + db * db) * INV2B);
            const float4* Pp = P4 + (size_t)np * 4;
#pragma unroll
            for (int j = 0; j < 4; ++j) {
                float4 v = Pp[j];
                bl[4 * j + 0] += wgt * v.x; bl[4 * j + 1] += wgt * v.y;
                bl[4 * j + 2] += wgt * v.z; bl[4 * j + 3] += wgt * v.w;
            }
        }
    }
    float inv_bn = 1.0f / ws[OFF_BN + pix];
#pragma unroll
    for (int i = 0; i < 16; ++i) bl[i] *= inv_bn;

    // q = u - M1@sp - M2@bl
    const float* U = ws + OFF_U + (size_t)pix * 16;
    float4* d4 = (float4*)dst;
    float qn[16];
#pragma unroll
    for (int i = 0; i < 16; ++i) {
        float acc = U[i];
#pragma unroll
        for (int j4 = 0; j4 < 4; ++j4) {
            float4 m1 = sM1[i * 4 + j4];
            float4 m2 = sM2[i * 4 + j4];
            acc -= m1.x * sp[4 * j4 + 0] + m1.y * sp[4 * j4 + 1]
                 + m1.z * sp[4 * j4 + 2] + m1.w * sp[4 * j4 + 3];
            acc -= m2.x * bl[4 * j4 + 0] + m2.y * bl[4 * j4 + 1]
                 + m2.z * bl[4 * j4 + 2] + m2.w * bl[4 * j4 + 3];
        }
        qn[i] = acc;
    }
#pragma unroll
    for (int j = 0; j < 4; ++j)
        d4[(size_t)pix * 4 + j] = make_float4(qn[4 * j], qn[4 * j + 1], qn[4 * j + 2], qn[4 * j + 3]);
}

// --------------------------------------------------------------------- launcher
extern "C" void kernel_launch(void* const* d_in, const int* in_sizes, int n_in,
                              void* d_out, int out_size, void* d_ws, size_t ws_size,
                              hipStream_t stream) {
    const float* img = (const float*)d_in[0];
    const float* ub  = (const float*)d_in[1];
    const float* ug  = (const float*)d_in[2];
    const float* Sw  = (const float*)d_in[3];
    const float* Bw  = (const float*)d_in[4];
    const float* Cm  = (const float*)d_in[5];
    const float* pbw = (const float*)d_in[6];
    const float* pgw = (const float*)d_in[7];
    float* ws  = (float*)d_ws;
    float* out = (float*)d_out;

    k_init<<<1, 512, 0, stream>>>(Sw, Bw, Cm, ws);
    k_prep<<<HW / 256, 256, 0, stream>>>(img, ub, ug, pbw, pgw, ws);

    for (int it = 0; it < NUM_ITERS; ++it) {
        const float* src = (it == 0) ? (ws + OFF_U) : (ws + OFF_Q);
        k_softmax<<<HW / 256, 256, 0, stream>>>(src, ws + OFF_P);
        k_convv<<<HW * 4 / 256, 256, 0, stream>>>(ws, (const float4*)(ws + OFF_P),
                                                  (float4*)(ws + OFF_T));
        float* dst = (it == NUM_ITERS - 1) ? out : (ws + OFF_Q);
        k_combine<<<HW / 256, 256, 0, stream>>>(ws, img, dst);
    }
}

// Round 3
// 433.200 us; speedup vs baseline: 1.2004x; 1.2004x over previous
//
#include <hip/hip_runtime.h>

// CRF-RNN forward, MI355X. Channel-last (H,W,16) internal layout, float4 ops.
// Per iteration: k_convv (vertical gaussian, sliding window) + k_combine
// (LDS-tiled horizontal gaussian + 5x5 bilateral + channel mix + q update +
// fused softmax for the next iteration, double-buffered P).

constexpr int H = 512, W = 512;
constexpr int HW = H * W;
constexpr int NUM_ITERS = 5;
constexpr float INV2A = 1.0f / (2.0f * 160.0f * 160.0f);
constexpr float INV2B = 1.0f / (2.0f * 3.0f * 3.0f);

// workspace layout (float offsets)
constexpr size_t OFF_U  = 0;                          // unaries  (H,W,16)
constexpr size_t OFF_PA = OFF_U  + (size_t)HW * 16;   // softmax buf A
constexpr size_t OFF_PB = OFF_PA + (size_t)HW * 16;   // softmax buf B
constexpr size_t OFF_T  = OFF_PB + (size_t)HW * 16;   // vertical-conv result
constexpr size_t OFF_SV = OFF_T  + (size_t)HW * 16;   // 1D spatial-norm table [512]
constexpr size_t OFF_KG = OFF_SV + 512;               // gauss taps [19] (pad 32)
constexpr size_t OFF_M1 = OFF_KG + 32;                // C@Sw  16x16 row-major
constexpr size_t OFF_M2 = OFF_M1 + 256;               // C@Bw  16x16 row-major
// total ~16.78M floats = 67.1 MB

// ---------------------------------------------------------------- init tables
__global__ void k_init(const float* __restrict__ Sw, const float* __restrict__ Bw,
                       const float* __restrict__ Cm, float* __restrict__ ws) {
    __shared__ float kg[19];
    int tid = threadIdx.x;
    if (tid < 19) { int t = tid - 9; kg[tid] = expf(-(float)(t * t) / 18.0f); }
    __syncthreads();
    if (tid < 19) ws[OFF_KG + tid] = kg[tid];
    if (tid < 512) {
        float s = 0.0f;
        for (int t = -9; t <= 9; ++t) {
            int yy = tid + t;
            if (yy >= 0 && yy < 512) s += kg[t + 9];
        }
        ws[OFF_SV + tid] = s;
    }
    if (tid < 256) {
        int r = tid >> 4, c = tid & 15;
        float a = 0.0f, b = 0.0f;
        for (int k = 0; k < 16; ++k) {
            float cv = Cm[r * 16 + k];
            a += cv * Sw[k * 16 + c];
            b += cv * Bw[k * 16 + c];
        }
        ws[OFF_M1 + tid] = a;
        ws[OFF_M2 + tid] = b;
    }
}

// ----------------------- unaries (transpose to HWD) + fused softmax -> P_A
__global__ __launch_bounds__(256) void k_prep(const float* __restrict__ ub,
                                              const float* __restrict__ ug,
                                              const float* __restrict__ pbw,
                                              const float* __restrict__ pgw,
                                              float* __restrict__ ws) {
    int pix = blockIdx.x * 256 + threadIdx.x;
    float bw = pbw[0], gw = pgw[0];

    float u[16];
#pragma unroll
    for (int i = 0; i < 16; ++i)
        u[i] = ub[(size_t)i * HW + pix] * bw + ug[(size_t)i * HW + pix] * gw;

    float4* U4 = (float4*)(ws + OFF_U);
#pragma unroll
    for (int j = 0; j < 4; ++j)
        U4[(size_t)pix * 4 + j] = make_float4(u[4 * j], u[4 * j + 1], u[4 * j + 2], u[4 * j + 3]);

    float m = u[0];
#pragma unroll
    for (int i = 1; i < 16; ++i) m = fmaxf(m, u[i]);
    float sum = 0.0f;
#pragma unroll
    for (int i = 0; i < 16; ++i) { u[i] = __expf(u[i] - m); sum += u[i]; }
    float inv = 1.0f / sum;
    float4* P4 = (float4*)(ws + OFF_PA);
#pragma unroll
    for (int j = 0; j < 4; ++j)
        P4[(size_t)pix * 4 + j] = make_float4(u[4 * j] * inv, u[4 * j + 1] * inv,
                                              u[4 * j + 2] * inv, u[4 * j + 3] * inv);
}

// ---------------- vertical 19-tap gaussian, sliding window: 8 outputs/thread
__global__ __launch_bounds__(256) void k_convv(const float* __restrict__ ws,
                                               const float4* __restrict__ P4,
                                               float4* __restrict__ T4) {
    int gtid = blockIdx.x * 256 + threadIdx.x;   // 2^17 threads
    int c4 = gtid & 3;
    int x  = (gtid >> 2) & 511;
    int yb = (gtid >> 11) << 3;                  // 0,8,...,504 (uniform per wave)

    float kg[19];
#pragma unroll
    for (int t = 0; t < 19; ++t) kg[t] = ws[OFF_KG + t];

    float4 acc[8];
#pragma unroll
    for (int k = 0; k < 8; ++k) acc[k] = make_float4(0.f, 0.f, 0.f, 0.f);

#pragma unroll
    for (int t = 0; t < 26; ++t) {
        int yy = yb + t - 9;
        float4 p = make_float4(0.f, 0.f, 0.f, 0.f);
        if ((unsigned)yy < (unsigned)H)
            p = P4[((size_t)(yy * W + x)) * 4 + c4];
        int k0 = (t - 18 > 0) ? t - 18 : 0;
        int k1 = (t < 7) ? t : 7;
#pragma unroll
        for (int k = k0; k <= k1; ++k) {
            float w = kg[t - k];
            acc[k].x += w * p.x; acc[k].y += w * p.y;
            acc[k].z += w * p.z; acc[k].w += w * p.w;
        }
    }
#pragma unroll
    for (int k = 0; k < 8; ++k)
        T4[((size_t)((yb + k) * W + x)) * 4 + c4] = acc[k];
}

// --- fused: hconv + /snorm + bilateral + /bnorm + channel mix + q (+ softmax)
// tile: 64x4 output pixels per 256-thread block, all reuse via LDS.
// LDS pixel stride = 20 floats (80 B) -> wave64 b128 reads cycle all 32 banks.
__global__ __launch_bounds__(256) void k_combine(const float* __restrict__ ws,
                                                 const float* __restrict__ img,
                                                 const float4* __restrict__ Psrc,
                                                 float4* __restrict__ dst,
                                                 int do_softmax) {
    __shared__ float sT[4 * 82 * 20];   // T tile:   4 rows x (64+18) px
    __shared__ float sP[8 * 68 * 20];   // P tile:   (4+4) rows x (64+4) px
    __shared__ float sI[8 * 68 * 3];    // rgb tile
    __shared__ float skg[20];
    __shared__ float sM1[256], sM2[256];

    int tid = threadIdx.x;
    int x0 = (blockIdx.x & 7) * 64;
    int y0 = (blockIdx.x >> 3) * 4;

    const float4* T4 = (const float4*)(ws + OFF_T);

    if (tid < 19) skg[tid] = ws[OFF_KG + tid];
    sM1[tid] = ws[OFF_M1 + tid];
    sM2[tid] = ws[OFF_M2 + tid];

    // stage T rows (x halo 9, no y halo)
    for (int e = tid; e < 4 * 82 * 4; e += 256) {
        int quad = e & 3;
        int t2 = e >> 2;
        int px = t2 % 82, row = t2 / 82;
        int gx = x0 - 9 + px;
        float4 v = make_float4(0.f, 0.f, 0.f, 0.f);
        if ((unsigned)gx < (unsigned)W)
            v = T4[((size_t)((y0 + row) * W + gx)) * 4 + quad];
        *(float4*)&sT[(row * 82 + px) * 20 + quad * 4] = v;
    }
    // stage P tile (halo 2 in x and y)
    for (int e = tid; e < 8 * 68 * 4; e += 256) {
        int quad = e & 3;
        int t2 = e >> 2;
        int px = t2 % 68, row = t2 / 68;
        int gx = x0 - 2 + px, gy = y0 - 2 + row;
        float4 v = make_float4(0.f, 0.f, 0.f, 0.f);
        if ((unsigned)gx < (unsigned)W && (unsigned)gy < (unsigned)H)
            v = Psrc[((size_t)(gy * W + gx)) * 4 + quad];
        *(float4*)&sP[(row * 68 + px) * 20 + quad * 4] = v;
    }
    // stage rgb tile
    for (int e = tid; e < 8 * 68; e += 256) {
        int px = e % 68, row = e / 68;
        int gx = x0 - 2 + px, gy = y0 - 2 + row;
        float r = 0.f, g = 0.f, b = 0.f;
        if ((unsigned)gx < (unsigned)W && (unsigned)gy < (unsigned)H) {
            const float* ip = img + ((size_t)(gy * W + gx)) * 3;
            r = ip[0]; g = ip[1]; b = ip[2];
        }
        sI[(row * 68 + px) * 3 + 0] = r;
        sI[(row * 68 + px) * 3 + 1] = g;
        sI[(row * 68 + px) * 3 + 2] = b;
    }
    __syncthreads();

    int ly = tid >> 6, lx = tid & 63;
    int y = y0 + ly, x = x0 + lx;

    float kg[19];
#pragma unroll
    for (int t = 0; t < 19; ++t) kg[t] = skg[t];

    // horizontal 19-tap conv from LDS
    float sp[16];
#pragma unroll
    for (int i = 0; i < 16; ++i) sp[i] = 0.0f;
#pragma unroll
    for (int t = 0; t < 19; ++t) {
        const float* base = &sT[(ly * 82 + lx + t) * 20];
        float k = kg[t];
#pragma unroll
        for (int j = 0; j < 4; ++j) {
            float4 v = *(const float4*)(base + j * 4);
            sp[4 * j + 0] += k * v.x; sp[4 * j + 1] += k * v.y;
            sp[4 * j + 2] += k * v.z; sp[4 * j + 3] += k * v.w;
        }
    }
    float inv_sn = 1.0f / (ws[OFF_SV + y] * ws[OFF_SV + x]);
#pragma unroll
    for (int i = 0; i < 16; ++i) sp[i] *= inv_sn;

    // 5x5 bilateral from LDS (bnorm accumulated on the fly)
    float bl[16];
#pragma unroll
    for (int i = 0; i < 16; ++i) bl[i] = 0.0f;
    float bn = 0.0f;
    const float* ic = &sI[((ly + 2) * 68 + lx + 2) * 3];
    float r0 = ic[0], g0 = ic[1], b0 = ic[2];
#pragma unroll
    for (int dy = 0; dy < 5; ++dy) {
        int gy = y + dy - 2;
        bool vy = (unsigned)gy < (unsigned)H;
#pragma unroll
        for (int dx = 0; dx < 5; ++dx) {
            int gx = x + dx - 2;
            const float* ip = &sI[((ly + dy) * 68 + lx + dx) * 3];
            float dr = r0 - ip[0], dg = g0 - ip[1], db = b0 - ip[2];
            float wgt = __expf(-(float)((dy - 2) * (dy - 2) + (dx - 2) * (dx - 2)) * INV2A
                               - (dr * dr + dg * dg + db * db) * INV2B);
            if (!(vy && (unsigned)gx < (unsigned)W)) wgt = 0.0f;
            bn += wgt;
            const float* pb = &sP[((ly + dy) * 68 + lx + dx) * 20];
#pragma unroll
            for (int j = 0; j < 4; ++j) {
                float4 v = *(const float4*)(pb + j * 4);
                bl[4 * j + 0] += wgt * v.x; bl[4 * j + 1] += wgt * v.y;
                bl[4 * j + 2] += wgt * v.z; bl[4 * j + 3] += wgt * v.w;
            }
        }
    }
    float inv_bn = 1.0f / bn;
#pragma unroll
    for (int i = 0; i < 16; ++i) bl[i] *= inv_bn;

    // q = U - M1@sp - M2@bl   (M rows via uniform-address LDS broadcast)
    size_t pix = (size_t)y * W + x;
    const float4* U4 = (const float4*)(ws + OFF_U);
    float qn[16];
#pragma unroll
    for (int i = 0; i < 16; ++i) {
        float acc = 0.0f;
#pragma unroll
        for (int j4 = 0; j4 < 4; ++j4) {
            float4 m1 = *(const float4*)&sM1[i * 16 + j4 * 4];
            float4 m2 = *(const float4*)&sM2[i * 16 + j4 * 4];
            acc += m1.x * sp[4 * j4 + 0] + m1.y * sp[4 * j4 + 1]
                 + m1.z * sp[4 * j4 + 2] + m1.w * sp[4 * j4 + 3];
            acc += m2.x * bl[4 * j4 + 0] + m2.y * bl[4 * j4 + 1]
                 + m2.z * bl[4 * j4 + 2] + m2.w * bl[4 * j4 + 3];
        }
        qn[i] = -acc;
    }
#pragma unroll
    for (int j = 0; j < 4; ++j) {
        float4 u = U4[pix * 4 + j];
        qn[4 * j + 0] += u.x; qn[4 * j + 1] += u.y;
        qn[4 * j + 2] += u.z; qn[4 * j + 3] += u.w;
    }

    if (do_softmax) {
        float m = qn[0];
#pragma unroll
        for (int i = 1; i < 16; ++i) m = fmaxf(m, qn[i]);
        float sum = 0.0f;
#pragma unroll
        for (int i = 0; i < 16; ++i) { qn[i] = __expf(qn[i] - m); sum += qn[i]; }
        float inv = 1.0f / sum;
#pragma unroll
        for (int i = 0; i < 16; ++i) qn[i] *= inv;
    }
#pragma unroll
    for (int j = 0; j < 4; ++j)
        dst[pix * 4 + j] = make_float4(qn[4 * j], qn[4 * j + 1], qn[4 * j + 2], qn[4 * j + 3]);
}

// --------------------------------------------------------------------- launcher
extern "C" void kernel_launch(void* const* d_in, const int* in_sizes, int n_in,
                              void* d_out, int out_size, void* d_ws, size_t ws_size,
                              hipStream_t stream) {
    const float* img = (const float*)d_in[0];
    const float* ub  = (const float*)d_in[1];
    const float* ug  = (const float*)d_in[2];
    const float* Sw  = (const float*)d_in[3];
    const float* Bw  = (const float*)d_in[4];
    const float* Cm  = (const float*)d_in[5];
    const float* pbw = (const float*)d_in[6];
    const float* pgw = (const float*)d_in[7];
    float* ws  = (float*)d_ws;
    float* out = (float*)d_out;

    k_init<<<1, 512, 0, stream>>>(Sw, Bw, Cm, ws);
    k_prep<<<HW / 256, 256, 0, stream>>>(ub, ug, pbw, pgw, ws);

    for (int it = 0; it < NUM_ITERS; ++it) {
        const float* Ps = (it & 1) ? (ws + OFF_PB) : (ws + OFF_PA);
        float* Pd       = (it & 1) ? (ws + OFF_PA) : (ws + OFF_PB);
        k_convv<<<HW * 4 / 8 / 256, 256, 0, stream>>>(ws, (const float4*)Ps,
                                                      (float4*)(ws + OFF_T));
        if (it < NUM_ITERS - 1)
            k_combine<<<HW / 256, 256, 0, stream>>>(ws, img, (const float4*)Ps,
                                                    (float4*)Pd, 1);
        else
            k_combine<<<HW / 256, 256, 0, stream>>>(ws, img, (const float4*)Ps,
                                                    (float4*)out, 0);
    }
}